// Round 1
// baseline (525.561 us; speedup 1.0000x reference)
//
#include <hip/hip_runtime.h>
#include <hip/hip_bf16.h>

#define T_TOK 2048
#define D_DIM 1024
#define H_DIM 2816
#define E_NUM 8

typedef __attribute__((ext_vector_type(8))) short short8;
typedef __attribute__((ext_vector_type(4))) float floatx4;

__device__ __forceinline__ unsigned short f2bf(float f) {
    unsigned int b = __float_as_uint(f);
    b += 0x7FFFu + ((b >> 16) & 1u);   // round-to-nearest-even
    return (unsigned short)(b >> 16);
}

// ---------------- x -> bf16 ----------------
__global__ __launch_bounds__(256) void k_convert_x(const float* __restrict__ x,
                                                   unsigned short* __restrict__ xb) {
    int i = blockIdx.x * 256 + threadIdx.x;
    float4 v = ((const float4*)x)[i];
    ushort4 o;
    o.x = f2bf(v.x); o.y = f2bf(v.y); o.z = f2bf(v.z); o.w = f2bf(v.w);
    ((ushort4*)xb)[i] = o;
}

// ---------------- gating: wave per token ----------------
__global__ __launch_bounds__(256) void k_gate(const float* __restrict__ x,
                                              const float* __restrict__ Wg,
                                              int* __restrict__ topi, float* __restrict__ topw,
                                              int* __restrict__ counts) {
    int wave = threadIdx.x >> 6, lane = threadIdx.x & 63;
    int t = blockIdx.x * 4 + wave;
    const float* xr = x + (size_t)t * D_DIM;
    float acc[E_NUM];
#pragma unroll
    for (int e = 0; e < E_NUM; ++e) acc[e] = 0.f;
    for (int i = 0; i < D_DIM / 64; ++i) {
        float xv = xr[lane + 64 * i];
#pragma unroll
        for (int e = 0; e < E_NUM; ++e) acc[e] += xv * Wg[e * D_DIM + lane + 64 * i];
    }
#pragma unroll
    for (int e = 0; e < E_NUM; ++e) {
#pragma unroll
        for (int s = 32; s > 0; s >>= 1) acc[e] += __shfl_xor(acc[e], s, 64);
    }
    if (lane == 0) {
        float mx = acc[0];
#pragma unroll
        for (int e = 1; e < E_NUM; ++e) mx = fmaxf(mx, acc[e]);
        float p[E_NUM], s = 0.f;
#pragma unroll
        for (int e = 0; e < E_NUM; ++e) { p[e] = expf(acc[e] - mx); s += p[e]; }
        int i0 = 0;
#pragma unroll
        for (int e = 1; e < E_NUM; ++e) if (p[e] > p[i0]) i0 = e;
        int i1 = (i0 == 0) ? 1 : 0;
#pragma unroll
        for (int e = 0; e < E_NUM; ++e) if (e != i0 && p[e] > p[i1]) i1 = e;
        float s0 = p[i0] / s, s1 = p[i1] / s;
        float d = s0 + s1 + 1e-20f;
        topi[t * 2] = i0; topi[t * 2 + 1] = i1;
        topw[t * 2] = s0 / d; topw[t * 2 + 1] = s1 / d;
        atomicAdd(&counts[i0], 1);
        atomicAdd(&counts[i1], 1);
    }
}

// ---------------- prefix scan over 8 counts ----------------
__global__ void k_scan(const int* __restrict__ counts, int* __restrict__ offs,
                       int* __restrict__ cursor) {
    if (threadIdx.x == 0) {
        int s = 0;
        for (int e = 0; e < E_NUM; ++e) { offs[e] = s; cursor[e] = s; s += counts[e]; }
        offs[E_NUM] = s;
    }
}

// ---------------- scatter tokens into per-expert lists ----------------
__global__ __launch_bounds__(256) void k_scatter(const int* __restrict__ topi,
                                                 const float* __restrict__ topw,
                                                 int* __restrict__ cursor,
                                                 int* __restrict__ ltok, float* __restrict__ lw) {
    int t = blockIdx.x * 256 + threadIdx.x;
#pragma unroll
    for (int k = 0; k < 2; ++k) {
        int e = topi[t * 2 + k];
        int pos = atomicAdd(&cursor[e], 1);
        ltok[pos] = t;
        lw[pos] = topw[t * 2 + k];
    }
}

// ---------------- GEMM 1&3: U = silu(x W1^T) * (x W3^T), per expert ----------------
// BM=128, BN=64 (per matrix), BK=64; 4 waves, each wave 32 rows x 64 cols, 2 accum sets.
__global__ __launch_bounds__(256) void k_gemm13(const unsigned short* __restrict__ xb,
                                                const float* __restrict__ W1,
                                                const float* __restrict__ W3,
                                                const int* __restrict__ ltok,
                                                const int* __restrict__ offs,
                                                const int* __restrict__ counts,
                                                unsigned short* __restrict__ U) {
    const int e = blockIdx.z;
    const int cnt = counts[e];
    const int mtile = blockIdx.y;
    if (mtile * 128 >= cnt) return;
    const int ntile = blockIdx.x;           // H/64 = 44
    const int off = offs[e];

    __shared__ __align__(16) unsigned short As[128 * 72];
    __shared__ __align__(16) unsigned short B1s[64 * 72];
    __shared__ __align__(16) unsigned short B3s[64 * 72];

    const int tid = threadIdx.x;
    const int lane = tid & 63, wave = tid >> 6;

    const unsigned short* aptr[4];
#pragma unroll
    for (int i = 0; i < 4; ++i) {
        int row = i * 32 + (tid >> 3);
        int g = mtile * 128 + row;
        if (g >= cnt) g = cnt - 1;          // clamp; results discarded on store
        int t = ltok[off + g];
        aptr[i] = xb + (size_t)t * D_DIM + (tid & 7) * 8;
    }
    const float* b1p = W1 + ((size_t)e * H_DIM + ntile * 64 + (tid >> 2)) * D_DIM + (tid & 3) * 16;
    const float* b3p = W3 + ((size_t)e * H_DIM + ntile * 64 + (tid >> 2)) * D_DIM + (tid & 3) * 16;

    floatx4 acc1[2][4], acc3[2][4];
#pragma unroll
    for (int i = 0; i < 2; ++i)
#pragma unroll
        for (int j = 0; j < 4; ++j) { acc1[i][j] = (floatx4)0.f; acc3[i][j] = (floatx4)0.f; }

    const int arow = tid >> 3, acol = (tid & 7) * 8;
    const int brow = tid >> 2, bcol = (tid & 3) * 16;

    for (int k0 = 0; k0 < D_DIM; k0 += 64) {
#pragma unroll
        for (int i = 0; i < 4; ++i) {
            uint4 v = *(const uint4*)(aptr[i] + k0);
            *(uint4*)&As[(i * 32 + arow) * 72 + acol] = v;
        }
#pragma unroll
        for (int j = 0; j < 4; ++j) {
            float4 f = *(const float4*)(b1p + k0 + j * 4);
            ushort4 o; o.x = f2bf(f.x); o.y = f2bf(f.y); o.z = f2bf(f.z); o.w = f2bf(f.w);
            *(ushort4*)&B1s[brow * 72 + bcol + j * 4] = o;
        }
#pragma unroll
        for (int j = 0; j < 4; ++j) {
            float4 f = *(const float4*)(b3p + k0 + j * 4);
            ushort4 o; o.x = f2bf(f.x); o.y = f2bf(f.y); o.z = f2bf(f.z); o.w = f2bf(f.w);
            *(ushort4*)&B3s[brow * 72 + bcol + j * 4] = o;
        }
        __syncthreads();
        const int fr = lane & 15, quad = lane >> 4;
#pragma unroll
        for (int kk = 0; kk < 64; kk += 32) {
            short8 a0 = *(const short8*)&As[(wave * 32 + fr) * 72 + kk + quad * 8];
            short8 a1 = *(const short8*)&As[(wave * 32 + 16 + fr) * 72 + kk + quad * 8];
#pragma unroll
            for (int ni = 0; ni < 4; ++ni) {
                short8 b1 = *(const short8*)&B1s[(ni * 16 + fr) * 72 + kk + quad * 8];
                acc1[0][ni] = __builtin_amdgcn_mfma_f32_16x16x32_bf16(a0, b1, acc1[0][ni], 0, 0, 0);
                acc1[1][ni] = __builtin_amdgcn_mfma_f32_16x16x32_bf16(a1, b1, acc1[1][ni], 0, 0, 0);
                short8 b3 = *(const short8*)&B3s[(ni * 16 + fr) * 72 + kk + quad * 8];
                acc3[0][ni] = __builtin_amdgcn_mfma_f32_16x16x32_bf16(a0, b3, acc3[0][ni], 0, 0, 0);
                acc3[1][ni] = __builtin_amdgcn_mfma_f32_16x16x32_bf16(a1, b3, acc3[1][ni], 0, 0, 0);
            }
        }
        __syncthreads();
    }

    const int col = lane & 15, quad = lane >> 4;
#pragma unroll
    for (int mi = 0; mi < 2; ++mi) {
#pragma unroll
        for (int r = 0; r < 4; ++r) {
            int row = wave * 32 + mi * 16 + quad * 4 + r;
            int g = mtile * 128 + row;
            if (g < cnt) {
                size_t base = (size_t)(off + g) * H_DIM + ntile * 64;
#pragma unroll
                for (int ni = 0; ni < 4; ++ni) {
                    float u1 = acc1[mi][ni][r];
                    float u3 = acc3[mi][ni][r];
                    float u = u1 / (1.f + __expf(-u1)) * u3;
                    U[base + ni * 16 + col] = f2bf(u);
                }
            }
        }
    }
}

// ---------------- GEMM 2: y += w * (U W2^T), per expert ----------------
// BM=128, BN=128, BK=64; 4 waves, each wave 32 rows x 128 cols.
__global__ __launch_bounds__(256) void k_gemm2(const unsigned short* __restrict__ U,
                                               const float* __restrict__ W2,
                                               const int* __restrict__ ltok,
                                               const float* __restrict__ lw,
                                               const int* __restrict__ offs,
                                               const int* __restrict__ counts,
                                               float* __restrict__ y) {
    const int e = blockIdx.z;
    const int cnt = counts[e];
    const int mtile = blockIdx.y;
    if (mtile * 128 >= cnt) return;
    const int ntile = blockIdx.x;           // D/128 = 8
    const int off = offs[e];

    __shared__ __align__(16) unsigned short As[128 * 72];
    __shared__ __align__(16) unsigned short Bs[128 * 72];

    const int tid = threadIdx.x, lane = tid & 63, wave = tid >> 6;

    const unsigned short* aptr[4];
#pragma unroll
    for (int i = 0; i < 4; ++i) {
        int row = i * 32 + (tid >> 3);
        int g = mtile * 128 + row;
        if (g >= cnt) g = cnt - 1;
        aptr[i] = U + (size_t)(off + g) * H_DIM + (tid & 7) * 8;
    }
    const float* bp = W2 + ((size_t)e * D_DIM + ntile * 128 + (tid >> 1)) * H_DIM + (tid & 1) * 32;

    floatx4 acc[2][8];
#pragma unroll
    for (int i = 0; i < 2; ++i)
#pragma unroll
        for (int j = 0; j < 8; ++j) acc[i][j] = (floatx4)0.f;

    const int arow = tid >> 3, acol = (tid & 7) * 8;
    const int brow = tid >> 1, bcol = (tid & 1) * 32;

    for (int k0 = 0; k0 < H_DIM; k0 += 64) {
#pragma unroll
        for (int i = 0; i < 4; ++i) {
            uint4 v = *(const uint4*)(aptr[i] + k0);
            *(uint4*)&As[(i * 32 + arow) * 72 + acol] = v;
        }
#pragma unroll
        for (int j = 0; j < 8; ++j) {
            float4 f = *(const float4*)(bp + k0 + j * 4);
            ushort4 o; o.x = f2bf(f.x); o.y = f2bf(f.y); o.z = f2bf(f.z); o.w = f2bf(f.w);
            *(ushort4*)&Bs[brow * 72 + bcol + j * 4] = o;
        }
        __syncthreads();
        const int fr = lane & 15, quad = lane >> 4;
#pragma unroll
        for (int kk = 0; kk < 64; kk += 32) {
            short8 a0 = *(const short8*)&As[(wave * 32 + fr) * 72 + kk + quad * 8];
            short8 a1 = *(const short8*)&As[(wave * 32 + 16 + fr) * 72 + kk + quad * 8];
#pragma unroll
            for (int ni = 0; ni < 8; ++ni) {
                short8 b = *(const short8*)&Bs[(ni * 16 + fr) * 72 + kk + quad * 8];
                acc[0][ni] = __builtin_amdgcn_mfma_f32_16x16x32_bf16(a0, b, acc[0][ni], 0, 0, 0);
                acc[1][ni] = __builtin_amdgcn_mfma_f32_16x16x32_bf16(a1, b, acc[1][ni], 0, 0, 0);
            }
        }
        __syncthreads();
    }

    const int col = lane & 15, quad = lane >> 4;
#pragma unroll
    for (int mi = 0; mi < 2; ++mi) {
#pragma unroll
        for (int r = 0; r < 4; ++r) {
            int row = wave * 32 + mi * 16 + quad * 4 + r;
            int g = mtile * 128 + row;
            if (g < cnt) {
                int p = off + g;
                int t = ltok[p];
                float w = lw[p];
                float* yr = y + (size_t)t * D_DIM + ntile * 128;
#pragma unroll
                for (int ni = 0; ni < 8; ++ni) {
                    atomicAdd(&yr[ni * 16 + col], acc[mi][ni][r] * w);
                }
            }
        }
    }
}

// ---------------- workspace layout ----------------
static const size_t OFF_XB   = 0;                         // T*D*2      = 4,194,304
static const size_t OFF_U    = 4194304;                   // 2T*H*2     = 23,068,672
static const size_t OFF_TOPI = OFF_U + 23068672;          // 2T ints
static const size_t OFF_TOPW = OFF_TOPI + 16384;          // 2T floats
static const size_t OFF_LTOK = OFF_TOPW + 16384;          // 2T ints
static const size_t OFF_LW   = OFF_LTOK + 16384;          // 2T floats
static const size_t OFF_META = OFF_LW + 16384;            // counts[8], cursor[8], offs[9]

extern "C" void kernel_launch(void* const* d_in, const int* in_sizes, int n_in,
                              void* d_out, int out_size, void* d_ws, size_t ws_size,
                              hipStream_t stream) {
    const float* x  = (const float*)d_in[0];
    const float* Wg = (const float*)d_in[1];
    const float* W1 = (const float*)d_in[2];
    const float* W2 = (const float*)d_in[3];
    const float* W3 = (const float*)d_in[4];
    float* y = (float*)d_out;
    char* ws = (char*)d_ws;

    unsigned short* xb = (unsigned short*)(ws + OFF_XB);
    unsigned short* U  = (unsigned short*)(ws + OFF_U);
    int*   topi = (int*)(ws + OFF_TOPI);
    float* topw = (float*)(ws + OFF_TOPW);
    int*   ltok = (int*)(ws + OFF_LTOK);
    float* lw   = (float*)(ws + OFF_LW);
    int*   meta = (int*)(ws + OFF_META);
    int* counts = meta;
    int* cursor = meta + 8;
    int* offs   = meta + 16;

    hipMemsetAsync(meta, 0, 64, stream);                                  // counts + cursor
    hipMemsetAsync(y, 0, (size_t)T_TOK * D_DIM * sizeof(float), stream);  // output accumulator

    k_convert_x<<<T_TOK * D_DIM / (256 * 4), 256, 0, stream>>>(x, xb);
    k_gate<<<T_TOK / 4, 256, 0, stream>>>(x, Wg, topi, topw, counts);
    k_scan<<<1, 64, 0, stream>>>(counts, offs, cursor);
    k_scatter<<<T_TOK / 256, 256, 0, stream>>>(topi, topw, cursor, ltok, lw);
    k_gemm13<<<dim3(H_DIM / 64, 16, E_NUM), 256, 0, stream>>>(xb, W1, W3, ltok, offs, counts, U);
    k_gemm2<<<dim3(D_DIM / 128, 16, E_NUM), 256, 0, stream>>>(U, W2, ltok, lw, offs, counts, y);
}